// Round 1
// baseline (2922.041 us; speedup 1.0000x reference)
//
#include <hip/hip_runtime.h>
#include <hip/hip_bf16.h>

#define T_TOK 8192
#define HDIM  1024
#define IDIM  4096
#define NEXP  8

typedef __bf16 bf16x8 __attribute__((ext_vector_type(8)));
typedef __bf16 bf16x4 __attribute__((ext_vector_type(4)));
typedef float  f32x4  __attribute__((ext_vector_type(4)));

// ---------------- Router: fp64 logits -> softmax -> top2 -> expert lists ----
__global__ __launch_bounds__(256) void router_kernel(
    const float* __restrict__ hs, const float* __restrict__ gpw,
    int* __restrict__ counts, int* __restrict__ lists, float* __restrict__ wlists)
{
    const int t   = blockIdx.x;
    const int tid = threadIdx.x;

    double acc[NEXP];
#pragma unroll
    for (int e = 0; e < NEXP; ++e) acc[e] = 0.0;

    const float* hrow = hs + (size_t)t * HDIM;
    for (int i = tid; i < HDIM; i += 256) {
        float x = hrow[i];
#pragma unroll
        for (int e = 0; e < NEXP; ++e)
            acc[e] += (double)x * (double)gpw[e * HDIM + i];
    }

    // wave (64-lane) shuffle reduce
#pragma unroll
    for (int e = 0; e < NEXP; ++e) {
#pragma unroll
        for (int off = 32; off > 0; off >>= 1)
            acc[e] += __shfl_down(acc[e], off);
    }

    __shared__ double wred[4][NEXP];
    const int wave = tid >> 6;
    const int lane = tid & 63;
    if (lane == 0) {
#pragma unroll
        for (int e = 0; e < NEXP; ++e) wred[wave][e] = acc[e];
    }
    __syncthreads();

    if (tid == 0) {
        double lg[NEXP];
#pragma unroll
        for (int e = 0; e < NEXP; ++e)
            lg[e] = wred[0][e] + wred[1][e] + wred[2][e] + wred[3][e];
        double mx = lg[0];
#pragma unroll
        for (int e = 1; e < NEXP; ++e) if (lg[e] > mx) mx = lg[e];
        double p[NEXP];
#pragma unroll
        for (int e = 0; e < NEXP; ++e) p[e] = exp(lg[e] - mx);
        // top-1 (first index on ties), then top-2
        int a = 0;
#pragma unroll
        for (int e = 1; e < NEXP; ++e) if (p[e] > p[a]) a = e;
        int b = (a == 0) ? 1 : 0;
#pragma unroll
        for (int e = 0; e < NEXP; ++e) if (e != a && p[e] > p[b]) b = e;

        double s  = p[a] + p[b];
        float  wa = (float)(p[a] / s);
        float  wb = (float)(p[b] / s);

        int pa = atomicAdd(&counts[a], 1);
        lists[a * T_TOK + pa]  = t;
        wlists[a * T_TOK + pa] = wa;
        int pb = atomicAdd(&counts[b], 1);
        lists[b * T_TOK + pb]  = t;
        wlists[b * T_TOK + pb] = wb;
    }
}

// ---------------- FFN1: h = silu(x@G) * (x@U) for one expert ----------------
// Tile: 64 slots x 64 I-cols, BK=32, 4 waves in 2x2, each wave 32x32 (2x2 MFMA)
__global__ __launch_bounds__(256) void ffn1_kernel(
    const float* __restrict__ hs, const float* __restrict__ gw,
    const float* __restrict__ uw, const int* __restrict__ counts,
    const int* __restrict__ lists, __bf16* __restrict__ hbuf, int e)
{
    const int cnt = counts[e];
    const int m0  = blockIdx.y * 64;
    if (m0 >= cnt) return;
    const int n0  = blockIdx.x * 64;
    const int tid = threadIdx.x;

    const size_t wbase = (size_t)e * HDIM * IDIM;
    const float* G = gw + wbase;
    const float* U = uw + wbase;

    __shared__ int    toks[64];
    __shared__ __bf16 As[64][40];   // [m][k], pad 8 -> 2-way-max bank alias
    __shared__ __bf16 Bg[64][40];   // [n][k] (transposed)
    __shared__ __bf16 Bu[64][40];

    if (tid < 64) {
        int idx   = m0 + tid;
        toks[tid] = (idx < cnt) ? lists[e * T_TOK + idx] : -1;
    }
    __syncthreads();

    const int a_r  = tid >> 3;          // 0..31
    const int a_k4 = (tid & 7) * 4;     // 0..28
    const int b_k  = tid >> 4;          // 0..15
    const int b_n4 = (tid & 15) * 4;    // 0..60

    const int wv   = tid >> 6;
    const int lane = tid & 63;
    const int wm   = (wv >> 1) * 32;
    const int wn   = (wv & 1) * 32;
    const int fr   = lane & 15;
    const int fq   = lane >> 4;

    f32x4 accg[2][2], accu[2][2];
#pragma unroll
    for (int i = 0; i < 2; ++i)
#pragma unroll
        for (int j = 0; j < 2; ++j) { accg[i][j] = (f32x4)0.0f; accu[i][j] = (f32x4)0.0f; }

    for (int kk = 0; kk < HDIM; kk += 32) {
        // stage A (gathered token rows), fp32 -> bf16
#pragma unroll
        for (int s = 0; s < 2; ++s) {
            int r   = a_r + s * 32;
            int tok = toks[r];
            float4 v = make_float4(0.f, 0.f, 0.f, 0.f);
            if (tok >= 0)
                v = *(const float4*)(hs + (size_t)tok * HDIM + kk + a_k4);
            bf16x4 pk;
            pk[0] = (__bf16)v.x; pk[1] = (__bf16)v.y; pk[2] = (__bf16)v.z; pk[3] = (__bf16)v.w;
            *(bf16x4*)(&As[r][a_k4]) = pk;
        }
        // stage B gate/up, transposed into [n][k]
#pragma unroll
        for (int s = 0; s < 2; ++s) {
            int k = b_k + s * 16;
            const float4 g4 = *(const float4*)(G + (size_t)(kk + k) * IDIM + n0 + b_n4);
            const float4 u4 = *(const float4*)(U + (size_t)(kk + k) * IDIM + n0 + b_n4);
            Bg[b_n4 + 0][k] = (__bf16)g4.x; Bg[b_n4 + 1][k] = (__bf16)g4.y;
            Bg[b_n4 + 2][k] = (__bf16)g4.z; Bg[b_n4 + 3][k] = (__bf16)g4.w;
            Bu[b_n4 + 0][k] = (__bf16)u4.x; Bu[b_n4 + 1][k] = (__bf16)u4.y;
            Bu[b_n4 + 2][k] = (__bf16)u4.z; Bu[b_n4 + 3][k] = (__bf16)u4.w;
        }
        __syncthreads();

        bf16x8 af[2], bgf[2], buf2[2];
#pragma unroll
        for (int mi = 0; mi < 2; ++mi)
            af[mi] = *(const bf16x8*)(&As[wm + mi * 16 + fr][fq * 8]);
#pragma unroll
        for (int ni = 0; ni < 2; ++ni) {
            bgf[ni]  = *(const bf16x8*)(&Bg[wn + ni * 16 + fr][fq * 8]);
            buf2[ni] = *(const bf16x8*)(&Bu[wn + ni * 16 + fr][fq * 8]);
        }
#pragma unroll
        for (int mi = 0; mi < 2; ++mi)
#pragma unroll
            for (int ni = 0; ni < 2; ++ni) {
                accg[mi][ni] = __builtin_amdgcn_mfma_f32_16x16x32_bf16(af[mi], bgf[ni],  accg[mi][ni], 0, 0, 0);
                accu[mi][ni] = __builtin_amdgcn_mfma_f32_16x16x32_bf16(af[mi], buf2[ni], accu[mi][ni], 0, 0, 0);
            }
        __syncthreads();
    }

    // epilogue: SwiGLU, store bf16 h
#pragma unroll
    for (int mi = 0; mi < 2; ++mi)
#pragma unroll
        for (int ni = 0; ni < 2; ++ni)
#pragma unroll
            for (int r = 0; r < 4; ++r) {
                int m    = wm + mi * 16 + fq * 4 + r;
                int slot = m0 + m;
                if (slot < cnt) {
                    float g = accg[mi][ni][r];
                    float u = accu[mi][ni][r];
                    float h = g * (1.0f / (1.0f + __expf(-g))) * u;
                    hbuf[(size_t)slot * IDIM + n0 + wn + ni * 16 + fr] = (__bf16)h;
                }
            }
}

// ---------------- FFN2: out[tok] += w * (h @ Down) for one expert -----------
__global__ __launch_bounds__(256) void ffn2_kernel(
    const __bf16* __restrict__ hbuf, const float* __restrict__ dw,
    const int* __restrict__ counts, const int* __restrict__ lists,
    const float* __restrict__ wlists, float* __restrict__ out, int e)
{
    const int cnt = counts[e];
    const int m0  = blockIdx.y * 64;
    if (m0 >= cnt) return;
    const int n0  = blockIdx.x * 64;
    const int tid = threadIdx.x;

    const float* D = dw + (size_t)e * IDIM * HDIM;

    __shared__ int    toks[64];
    __shared__ float  wts[64];
    __shared__ __bf16 As[64][40];
    __shared__ __bf16 Bd[64][40];

    if (tid < 64) {
        int idx  = m0 + tid;
        bool val = idx < cnt;
        toks[tid] = val ? lists[e * T_TOK + idx]  : -1;
        wts[tid]  = val ? wlists[e * T_TOK + idx] : 0.f;
    }
    __syncthreads();

    const int a_r  = tid >> 3;
    const int a_k4 = (tid & 7) * 4;
    const int b_k  = tid >> 4;
    const int b_n4 = (tid & 15) * 4;

    const int wv   = tid >> 6;
    const int lane = tid & 63;
    const int wm   = (wv >> 1) * 32;
    const int wn   = (wv & 1) * 32;
    const int fr   = lane & 15;
    const int fq   = lane >> 4;

    f32x4 acc[2][2];
#pragma unroll
    for (int i = 0; i < 2; ++i)
#pragma unroll
        for (int j = 0; j < 2; ++j) acc[i][j] = (f32x4)0.0f;

    for (int kk = 0; kk < IDIM; kk += 32) {
        // stage A: h rows already bf16, direct copy
#pragma unroll
        for (int s = 0; s < 2; ++s) {
            int r = a_r + s * 32;
            bf16x4 v = *(const bf16x4*)(hbuf + (size_t)(m0 + r) * IDIM + kk + a_k4);
            *(bf16x4*)(&As[r][a_k4]) = v;
        }
        // stage B down, transposed
#pragma unroll
        for (int s = 0; s < 2; ++s) {
            int k = b_k + s * 16;
            const float4 d4 = *(const float4*)(D + (size_t)(kk + k) * HDIM + n0 + b_n4);
            Bd[b_n4 + 0][k] = (__bf16)d4.x; Bd[b_n4 + 1][k] = (__bf16)d4.y;
            Bd[b_n4 + 2][k] = (__bf16)d4.z; Bd[b_n4 + 3][k] = (__bf16)d4.w;
        }
        __syncthreads();

        bf16x8 af[2], bf[2];
#pragma unroll
        for (int mi = 0; mi < 2; ++mi)
            af[mi] = *(const bf16x8*)(&As[wm + mi * 16 + fr][fq * 8]);
#pragma unroll
        for (int ni = 0; ni < 2; ++ni)
            bf[ni] = *(const bf16x8*)(&Bd[wn + ni * 16 + fr][fq * 8]);
#pragma unroll
        for (int mi = 0; mi < 2; ++mi)
#pragma unroll
            for (int ni = 0; ni < 2; ++ni)
                acc[mi][ni] = __builtin_amdgcn_mfma_f32_16x16x32_bf16(af[mi], bf[ni], acc[mi][ni], 0, 0, 0);
        __syncthreads();
    }

    // epilogue: out[tok] += w * y   (expert launches serialized -> no races)
#pragma unroll
    for (int mi = 0; mi < 2; ++mi)
#pragma unroll
        for (int ni = 0; ni < 2; ++ni)
#pragma unroll
            for (int r = 0; r < 4; ++r) {
                int m   = wm + mi * 16 + fq * 4 + r;
                int tok = toks[m];
                if (tok >= 0) {
                    size_t o = (size_t)tok * HDIM + n0 + wn + ni * 16 + fr;
                    out[o] += wts[m] * acc[mi][ni][r];
                }
            }
}

// ---------------------------------------------------------------------------
extern "C" void kernel_launch(void* const* d_in, const int* in_sizes, int n_in,
                              void* d_out, int out_size, void* d_ws, size_t ws_size,
                              hipStream_t stream)
{
    const float* hs  = (const float*)d_in[0];
    const float* gpw = (const float*)d_in[1];
    const float* gw  = (const float*)d_in[2];
    const float* uw  = (const float*)d_in[3];
    const float* dw  = (const float*)d_in[4];
    float* out = (float*)d_out;

    char* p = (char*)d_ws;
    int*   counts = (int*)p;                     p += 256;
    int*   lists  = (int*)p;                     p += (size_t)NEXP * T_TOK * sizeof(int);
    float* wl     = (float*)p;                   p += (size_t)NEXP * T_TOK * sizeof(float);
    __bf16* hbuf  = (__bf16*)p;                  // T_TOK * IDIM bf16 = 64 MiB

    hipMemsetAsync(counts, 0, 256, stream);
    hipMemsetAsync(out, 0, (size_t)T_TOK * HDIM * sizeof(float), stream);

    router_kernel<<<T_TOK, 256, 0, stream>>>(hs, gpw, counts, lists, wl);

    for (int e = 0; e < NEXP; ++e) {
        ffn1_kernel<<<dim3(IDIM / 64, T_TOK / 64), 256, 0, stream>>>(
            hs, gw, uw, counts, lists, hbuf, e);
        ffn2_kernel<<<dim3(HDIM / 64, T_TOK / 64), 256, 0, stream>>>(
            hbuf, dw, counts, lists, wl, out, e);
    }
}

// Round 2
// 1108.561 us; speedup vs baseline: 2.6359x; 2.6359x over previous
//
#include <hip/hip_runtime.h>
#include <hip/hip_bf16.h>

#define T_TOK 8192
#define HDIM  1024
#define IDIM  4096
#define NEXP  8

typedef __bf16 bf16x8 __attribute__((ext_vector_type(8)));
typedef __bf16 bf16x4 __attribute__((ext_vector_type(4)));
typedef float  f32x4  __attribute__((ext_vector_type(4)));

typedef __attribute__((address_space(3))) unsigned int       lds_u32;
typedef const __attribute__((address_space(1))) unsigned int glb_u32;

__device__ __forceinline__ void gld16(void* lds, const void* g) {
    // async global->LDS, 16B per lane; LDS dest = wave-uniform base + lane*16
    __builtin_amdgcn_global_load_lds((glb_u32*)g, (lds_u32*)lds, 16, 0, 0);
}

// ---------------- hs fp32 -> bf16 ------------------------------------------
__global__ __launch_bounds__(256) void convert_hs_kernel(
    const float* __restrict__ hs, __bf16* __restrict__ hsb)
{
    size_t i = ((size_t)blockIdx.x * 256 + threadIdx.x) * 8;
    float4 a = *(const float4*)(hs + i);
    float4 b = *(const float4*)(hs + i + 4);
    bf16x8 v;
    v[0] = (__bf16)a.x; v[1] = (__bf16)a.y; v[2] = (__bf16)a.z; v[3] = (__bf16)a.w;
    v[4] = (__bf16)b.x; v[5] = (__bf16)b.y; v[6] = (__bf16)b.z; v[7] = (__bf16)b.w;
    *(bf16x8*)(hsb + i) = v;
}

// ---------------- weights fp32 [K][N] -> bf16 [N][K] (per expert) ----------
__global__ __launch_bounds__(256) void transpose_w_kernel(
    const float* __restrict__ gw, const float* __restrict__ uw,
    const float* __restrict__ dw,
    __bf16* __restrict__ Gt, __bf16* __restrict__ Ut, __bf16* __restrict__ Dt)
{
    const int z = blockIdx.y, mat = z >> 3, e = z & 7;
    const float* src; __bf16* dst; int R, C;
    if (mat == 0)      { src = gw; dst = Gt; R = HDIM; C = IDIM; }
    else if (mat == 1) { src = uw; dst = Ut; R = HDIM; C = IDIM; }
    else               { src = dw; dst = Dt; R = IDIM; C = HDIM; }
    src += (size_t)e * HDIM * IDIM;
    dst += (size_t)e * HDIM * IDIM;

    const int tilesC = C >> 6;
    const int tx = blockIdx.x % tilesC, ty = blockIdx.x / tilesC;
    const int r0 = ty * 64, c0 = tx * 64;

    __shared__ __bf16 Lt[64][72];   // [c][r], pad 72 -> 16B-aligned rows

    const int tr  = threadIdx.x >> 4;         // 0..15
    const int tc4 = (threadIdx.x & 15) * 4;   // 0..60
#pragma unroll
    for (int p = 0; p < 4; ++p) {
        int r = p * 16 + tr;
        float4 v = *(const float4*)(src + (size_t)(r0 + r) * C + c0 + tc4);
        Lt[tc4 + 0][r] = (__bf16)v.x;
        Lt[tc4 + 1][r] = (__bf16)v.y;
        Lt[tc4 + 2][r] = (__bf16)v.z;
        Lt[tc4 + 3][r] = (__bf16)v.w;
    }
    __syncthreads();

    const int oc  = threadIdx.x >> 3;         // 0..31
    const int or8 = (threadIdx.x & 7) * 8;    // 0..56
#pragma unroll
    for (int p = 0; p < 2; ++p) {
        int c = oc + p * 32;
        bf16x8 v = *(const bf16x8*)(&Lt[c][or8]);
        *(bf16x8*)(dst + (size_t)(c0 + c) * R + r0 + or8) = v;
    }
}

// ---------------- router: fp64 logits, top-2, no atomics --------------------
__global__ __launch_bounds__(256) void router_kernel(
    const float* __restrict__ hs, const float* __restrict__ gpw,
    int* __restrict__ ca, int* __restrict__ cb,
    float* __restrict__ wa, float* __restrict__ wb)
{
    const int wv = threadIdx.x >> 6, lane = threadIdx.x & 63;
    const int t  = blockIdx.x * 4 + wv;
    const float* hrow = hs + (size_t)t * HDIM;

    double acc[NEXP];
#pragma unroll
    for (int e = 0; e < NEXP; ++e) acc[e] = 0.0;

#pragma unroll
    for (int it = 0; it < HDIM / 64; ++it) {
        int i = lane + it * 64;
        double x = (double)hrow[i];
#pragma unroll
        for (int e = 0; e < NEXP; ++e)
            acc[e] += x * (double)gpw[e * HDIM + i];
    }
#pragma unroll
    for (int e = 0; e < NEXP; ++e)
#pragma unroll
        for (int m = 32; m > 0; m >>= 1)
            acc[e] += __shfl_xor(acc[e], m);

    if (lane == 0) {
        int a = 0;
#pragma unroll
        for (int e = 1; e < NEXP; ++e) if (acc[e] > acc[a]) a = e;
        int b = (a == 0) ? 1 : 0;
#pragma unroll
        for (int e = 0; e < NEXP; ++e) if (e != a && acc[e] > acc[b]) b = e;
        double wA = 1.0 / (1.0 + exp(acc[b] - acc[a]));  // = p_a/(p_a+p_b)
        ca[t] = a; cb[t] = b;
        wa[t] = (float)wA; wb[t] = (float)(1.0 - wA);
    }
}

// ---------------- build per-expert lists (deterministic scan) ---------------
__global__ __launch_bounds__(256) void build_lists_kernel(
    const int* __restrict__ ca, const int* __restrict__ cb,
    const float* __restrict__ wa, const float* __restrict__ wb,
    int* __restrict__ lists, float* __restrict__ wlists, int* __restrict__ counts)
{
    const int e = blockIdx.x;
    const int tid = threadIdx.x, wv = tid >> 6, lane = tid & 63;
    __shared__ int wsum[4];
    int base = 0;
    for (int t0 = 0; t0 < T_TOK; t0 += 256) {
        int t  = t0 + tid;
        int m2 = (cb[t] == e);
        int m  = (ca[t] == e) | m2;
        unsigned long long bal = __ballot(m);
        int my   = __popcll(bal & ((1ull << lane) - 1ull));
        if (lane == 0) wsum[wv] = __popcll(bal);
        __syncthreads();
        int off = 0;
        for (int w2 = 0; w2 < wv; ++w2) off += wsum[w2];
        int tot = wsum[0] + wsum[1] + wsum[2] + wsum[3];
        if (m) {
            int pos = base + off + my;
            lists[e * T_TOK + pos]  = t * 2 + m2;
            wlists[e * T_TOK + pos] = m2 ? wb[t] : wa[t];
        }
        base += tot;
        __syncthreads();
    }
    if (tid == 0) counts[e] = base;
}

// ---------------- FFN1: h = silu(x@G)*(x@U), 128x128 tile, BK=32 ------------
__global__ __launch_bounds__(256, 2) void ffn1_kernel(
    const __bf16* __restrict__ hsb, const __bf16* __restrict__ Gt,
    const __bf16* __restrict__ Ut, const int* __restrict__ counts,
    const int* __restrict__ lists, __bf16* __restrict__ hbuf)
{
    const int e   = blockIdx.z;
    const int cnt = counts[e];
    const int m0  = blockIdx.y * 128;
    if (m0 >= cnt) return;
    const int n0  = blockIdx.x * 128;
    const int tid = threadIdx.x;
    const int wv  = tid >> 6, lane = tid & 63;

    __shared__ int    toks[128];
    __shared__ __bf16 As[128][32];
    __shared__ __bf16 Bg[128][32];
    __shared__ __bf16 Bu[128][32];

    if (tid < 128) {
        int idx = m0 + tid;
        toks[tid] = lists[e * T_TOK + (idx < cnt ? idx : 0)];
    }
    __syncthreads();

    const int rr  = tid >> 2;      // 0..63
    const int seg = tid & 3;       // 0..3 (16B segment)
    const __bf16* Ge = Gt + (size_t)e * IDIM * HDIM;
    const __bf16* Ue = Ut + (size_t)e * IDIM * HDIM;
    const __bf16* gA0 = hsb + (size_t)(toks[rr] >> 1)      * HDIM + seg * 8;
    const __bf16* gA1 = hsb + (size_t)(toks[64 + rr] >> 1) * HDIM + seg * 8;
    const __bf16* gG0 = Ge + (size_t)(n0 + rr)      * HDIM + seg * 8;
    const __bf16* gG1 = Ge + (size_t)(n0 + 64 + rr) * HDIM + seg * 8;
    const __bf16* gU0 = Ue + (size_t)(n0 + rr)      * HDIM + seg * 8;
    const __bf16* gU1 = Ue + (size_t)(n0 + 64 + rr) * HDIM + seg * 8;

    void* lA0 = &As[wv * 16][0];      void* lA1 = &As[64 + wv * 16][0];
    void* lG0 = &Bg[wv * 16][0];      void* lG1 = &Bg[64 + wv * 16][0];
    void* lU0 = &Bu[wv * 16][0];      void* lU1 = &Bu[64 + wv * 16][0];

    const int wm = (wv >> 1) * 64, wn = (wv & 1) * 64;
    const int fr = lane & 15, fq = lane >> 4;

    f32x4 accg[4][4], accu[4][4];
#pragma unroll
    for (int i = 0; i < 4; ++i)
#pragma unroll
        for (int j = 0; j < 4; ++j) { accg[i][j] = (f32x4)0.0f; accu[i][j] = (f32x4)0.0f; }

    for (int kk = 0; kk < HDIM; kk += 32) {
        gld16(lA0, gA0); gld16(lA1, gA1);
        gld16(lG0, gG0); gld16(lG1, gG1);
        gld16(lU0, gU0); gld16(lU1, gU1);
        gA0 += 32; gA1 += 32; gG0 += 32; gG1 += 32; gU0 += 32; gU1 += 32;
        __syncthreads();

        bf16x8 a[4];
#pragma unroll
        for (int mi = 0; mi < 4; ++mi)
            a[mi] = *(const bf16x8*)(&As[wm + mi * 16 + fr][fq * 8]);
#pragma unroll
        for (int ni = 0; ni < 4; ++ni) {
            bf16x8 bg = *(const bf16x8*)(&Bg[wn + ni * 16 + fr][fq * 8]);
            bf16x8 bu = *(const bf16x8*)(&Bu[wn + ni * 16 + fr][fq * 8]);
#pragma unroll
            for (int mi = 0; mi < 4; ++mi) {
                accg[mi][ni] = __builtin_amdgcn_mfma_f32_16x16x32_bf16(a[mi], bg, accg[mi][ni], 0, 0, 0);
                accu[mi][ni] = __builtin_amdgcn_mfma_f32_16x16x32_bf16(a[mi], bu, accu[mi][ni], 0, 0, 0);
            }
        }
        __syncthreads();
    }

#pragma unroll
    for (int mi = 0; mi < 4; ++mi)
#pragma unroll
        for (int r = 0; r < 4; ++r) {
            int row  = wm + mi * 16 + fq * 4 + r;
            int slot = m0 + row;
            if (slot < cnt) {
                __bf16* dst = hbuf + (size_t)toks[row] * IDIM + n0 + wn + fr;
#pragma unroll
                for (int ni = 0; ni < 4; ++ni) {
                    float g = accg[mi][ni][r], u = accu[mi][ni][r];
                    float h = g * (1.0f / (1.0f + __expf(-g))) * u;
                    dst[ni * 16] = (__bf16)h;
                }
            }
        }
}

// ---------------- FFN2: out[tok] += w * (h @ Dt), 128x128 tile --------------
__global__ __launch_bounds__(256, 2) void ffn2_kernel(
    const __bf16* __restrict__ hbuf, const __bf16* __restrict__ Dt,
    const int* __restrict__ counts, const int* __restrict__ lists,
    const float* __restrict__ wlists, float* __restrict__ out)
{
    const int e   = blockIdx.z;
    const int cnt = counts[e];
    const int m0  = blockIdx.y * 128;
    if (m0 >= cnt) return;
    const int n0  = blockIdx.x * 128;
    const int tid = threadIdx.x;
    const int wv  = tid >> 6, lane = tid & 63;

    __shared__ int    toks[128];
    __shared__ float  wts[128];
    __shared__ __bf16 As[128][32];
    __shared__ __bf16 Bd[128][32];

    if (tid < 128) {
        int idx  = m0 + tid;
        int cidx = idx < cnt ? idx : 0;
        toks[tid] = lists[e * T_TOK + cidx];
        wts[tid]  = wlists[e * T_TOK + cidx];
    }
    __syncthreads();

    const int rr  = tid >> 2;
    const int seg = tid & 3;
    const __bf16* De  = Dt + (size_t)e * HDIM * IDIM;
    const __bf16* gA0 = hbuf + (size_t)toks[rr]      * IDIM + seg * 8;
    const __bf16* gA1 = hbuf + (size_t)toks[64 + rr] * IDIM + seg * 8;
    const __bf16* gD0 = De + (size_t)(n0 + rr)      * IDIM + seg * 8;
    const __bf16* gD1 = De + (size_t)(n0 + 64 + rr) * IDIM + seg * 8;

    void* lA0 = &As[wv * 16][0];  void* lA1 = &As[64 + wv * 16][0];
    void* lD0 = &Bd[wv * 16][0];  void* lD1 = &Bd[64 + wv * 16][0];

    const int wm = (wv >> 1) * 64, wn = (wv & 1) * 64;
    const int fr = lane & 15, fq = lane >> 4;

    f32x4 acc[4][4];
#pragma unroll
    for (int i = 0; i < 4; ++i)
#pragma unroll
        for (int j = 0; j < 4; ++j) acc[i][j] = (f32x4)0.0f;

    for (int kk = 0; kk < IDIM; kk += 32) {
        gld16(lA0, gA0); gld16(lA1, gA1);
        gld16(lD0, gD0); gld16(lD1, gD1);
        gA0 += 32; gA1 += 32; gD0 += 32; gD1 += 32;
        __syncthreads();

        bf16x8 a[4], b[4];
#pragma unroll
        for (int mi = 0; mi < 4; ++mi)
            a[mi] = *(const bf16x8*)(&As[wm + mi * 16 + fr][fq * 8]);
#pragma unroll
        for (int ni = 0; ni < 4; ++ni)
            b[ni] = *(const bf16x8*)(&Bd[wn + ni * 16 + fr][fq * 8]);
#pragma unroll
        for (int mi = 0; mi < 4; ++mi)
#pragma unroll
            for (int ni = 0; ni < 4; ++ni)
                acc[mi][ni] = __builtin_amdgcn_mfma_f32_16x16x32_bf16(a[mi], b[ni], acc[mi][ni], 0, 0, 0);
        __syncthreads();
    }

#pragma unroll
    for (int mi = 0; mi < 4; ++mi)
#pragma unroll
        for (int r = 0; r < 4; ++r) {
            int row  = wm + mi * 16 + fq * 4 + r;
            int slot = m0 + row;
            if (slot < cnt) {
                int   tok = toks[row] >> 1;
                float w   = wts[row];
                float* dst = out + (size_t)tok * HDIM + n0 + wn + fr;
#pragma unroll
                for (int ni = 0; ni < 4; ++ni)
                    atomicAdd(&dst[ni * 16], w * acc[mi][ni][r]);
            }
        }
}

// ---------------------------------------------------------------------------
extern "C" void kernel_launch(void* const* d_in, const int* in_sizes, int n_in,
                              void* d_out, int out_size, void* d_ws, size_t ws_size,
                              hipStream_t stream)
{
    const float* hs  = (const float*)d_in[0];
    const float* gpw = (const float*)d_in[1];
    const float* gw  = (const float*)d_in[2];
    const float* uw  = (const float*)d_in[3];
    const float* dw  = (const float*)d_in[4];
    float* out = (float*)d_out;

    char* p = (char*)d_ws;
    __bf16* hsb  = (__bf16*)p;  p += (size_t)T_TOK * HDIM * 2;            // 16 MB
    __bf16* Gt   = (__bf16*)p;  p += (size_t)NEXP * IDIM * HDIM * 2;      // 64 MB
    __bf16* Ut   = (__bf16*)p;  p += (size_t)NEXP * IDIM * HDIM * 2;      // 64 MB
    __bf16* Dt   = (__bf16*)p;  p += (size_t)NEXP * HDIM * IDIM * 2;      // 64 MB
    __bf16* hbuf = (__bf16*)p;  p += (size_t)2 * T_TOK * IDIM * 2;        // 128 MB
    int*    lists  = (int*)p;   p += (size_t)NEXP * T_TOK * 4;
    float*  wlists = (float*)p; p += (size_t)NEXP * T_TOK * 4;
    int*    ca = (int*)p;       p += (size_t)T_TOK * 4;
    int*    cb = (int*)p;       p += (size_t)T_TOK * 4;
    float*  wa = (float*)p;     p += (size_t)T_TOK * 4;
    float*  wb = (float*)p;     p += (size_t)T_TOK * 4;
    int*    counts = (int*)p;

    hipMemsetAsync(out, 0, (size_t)T_TOK * HDIM * sizeof(float), stream);

    convert_hs_kernel<<<T_TOK * HDIM / 2048, 256, 0, stream>>>(hs, hsb);
    transpose_w_kernel<<<dim3(1024, 24), 256, 0, stream>>>(gw, uw, dw, Gt, Ut, Dt);
    router_kernel<<<T_TOK / 4, 256, 0, stream>>>(hs, gpw, ca, cb, wa, wb);
    build_lists_kernel<<<NEXP, 256, 0, stream>>>(ca, cb, wa, wb, lists, wlists, counts);

    ffn1_kernel<<<dim3(IDIM / 128, T_TOK / 128, NEXP), 256, 0, stream>>>(
        hsb, Gt, Ut, counts, lists, hbuf);
    ffn2_kernel<<<dim3(HDIM / 128, T_TOK / 128, NEXP), 256, 0, stream>>>(
        hbuf, Dt, counts, lists, wlists, out);
}